// Round 2
// baseline (25.998 us; speedup 1.0000x reference)
//
#include <hip/hip_runtime.h>
#include <cfloat>
#include <cmath>

#define RS 7   // ROI pool output size

// features: (B=2, C=256, H=50, W=50) f32
// boxes:    (B=2, Nb=64, 4) f32  -> N=128 boxes
// out:      (N=128, C=256, 7, 7) f32
// One thread per (n, c, i) row-bin -> computes 7 outputs (all j).
__global__ void roi_pool_rows(const float* __restrict__ features,
                              const float* __restrict__ boxes,
                              const int* __restrict__ image_size_p,
                              float* __restrict__ out,
                              int total_rows) {
    int t = blockIdx.x * blockDim.x + threadIdx.x;
    if (t >= total_rows) return;

    const int C = 256, H = 50, W = 50;

    int i  = t % RS;          // row-bin index 0..6
    int nc = t / RS;
    int c  = nc & (C - 1);
    int n  = nc >> 8;         // box index 0..127
    int b  = n >> 6;          // batch index

    float img = (float)image_size_p[0];
    float scale_h = (float)H / img;   // 0.0625 for 800
    float scale_w = (float)W / img;

    float4 bb = *reinterpret_cast<const float4*>(boxes + (size_t)n * 4);

    // jnp.round = round half to even = rintf (FE_TONEAREST default)
    int x1 = max(0, (int)rintf(bb.x * scale_w));
    int y1 = max(0, (int)rintf(bb.y * scale_h));
    int x2 = min(W, (int)rintf((bb.x + bb.z) * scale_w) + 1);
    int y2 = min(H, (int)rintf((bb.y + bb.w) * scale_h) + 1);
    if (x2 <= x1) x2 = min(x1 + 1, W);
    if (y2 <= y1) y2 = min(y1 + 1, H);

    int rh = y2 - y1;
    int rw = x2 - x1;

    int hs = y1 + (i * rh) / RS;
    int he = y1 + ((i + 1) * rh + RS - 1) / RS;

    // column-bin bounds, fully unrolled -> registers
    int ws[RS], we[RS];
#pragma unroll
    for (int j = 0; j < RS; ++j) {
        ws[j] = x1 + (j * rw) / RS;
        we[j] = x1 + ((j + 1) * rw + RS - 1) / RS;
    }

    const float* fplane = features + (size_t)(b * C + c) * (size_t)(H * W);

    float m[RS];
#pragma unroll
    for (int j = 0; j < RS; ++j) m[j] = -FLT_MAX;

    for (int r = hs; r < he; ++r) {
        const float* row = fplane + r * W;
#pragma unroll
        for (int j = 0; j < RS; ++j) {
            float mm = m[j];
            for (int q = ws[j]; q < we[j]; ++q) {
                mm = fmaxf(mm, row[q]);
            }
            m[j] = mm;
        }
    }

    float* op = out + (size_t)t * RS;
#pragma unroll
    for (int j = 0; j < RS; ++j) op[j] = m[j];
}

extern "C" void kernel_launch(void* const* d_in, const int* in_sizes, int n_in,
                              void* d_out, int out_size, void* d_ws, size_t ws_size,
                              hipStream_t stream) {
    const float* features = (const float*)d_in[0];
    const float* boxes    = (const float*)d_in[1];
    const int*   img_sz   = (const int*)d_in[2];
    float* out = (float*)d_out;

    int total_rows = out_size / RS;     // 128 * 256 * 7 = 229376
    int block = 256;
    int grid = (total_rows + block - 1) / block;
    roi_pool_rows<<<grid, block, 0, stream>>>(features, boxes, img_sz, out, total_rows);
}

// Round 3
// 17.799 us; speedup vs baseline: 1.4606x; 1.4606x over previous
//
#include <hip/hip_runtime.h>
#include <cfloat>
#include <cmath>

#define RS 7   // ROI pool output size

// features: (B=2, C=256, H=50, W=50) f32
// boxes:    (B=2, Nb=64, 4) f32  -> N=128 boxes
// out:      (N=128, C=256, 7, 7) f32
//
// One thread per output element. Box geometry guarantees rw, rh <= 14
// (w,h < 200 px, scale = 50/800), so each bin spans <= 3 rows x 3 cols:
// bin = ceil(frac + r/7) <= ceil(<1 + 2) = 3. We issue 9 unconditional
// loads at clamped coords; duplicates are idempotent under fmax.
__global__ void roi_pool_kernel(const float* __restrict__ features,
                                const float* __restrict__ boxes,
                                const int* __restrict__ image_size_p,
                                float* __restrict__ out,
                                int total) {
    int idx = blockIdx.x * blockDim.x + threadIdx.x;
    if (idx >= total) return;

    const int C = 256, H = 50, W = 50;

    int j = idx % RS;
    int t = idx / RS;
    int i = t % RS;
    t /= RS;
    int c = t & (C - 1);
    int n = t >> 8;          // box index 0..127
    int b = n >> 6;          // batch index

    float img = (float)image_size_p[0];
    float scale_h = (float)H / img;   // 0.0625 for 800
    float scale_w = (float)W / img;

    float4 bb = *reinterpret_cast<const float4*>(boxes + (size_t)n * 4);

    // jnp.round = round half to even = rintf (FE_TONEAREST default)
    int x1 = max(0, (int)rintf(bb.x * scale_w));
    int y1 = max(0, (int)rintf(bb.y * scale_h));
    int x2 = min(W, (int)rintf((bb.x + bb.z) * scale_w) + 1);
    int y2 = min(H, (int)rintf((bb.y + bb.w) * scale_h) + 1);
    if (x2 <= x1) x2 = min(x1 + 1, W);
    if (y2 <= y1) y2 = min(y1 + 1, H);

    int rh = y2 - y1;
    int rw = x2 - x1;

    int hs = y1 + (i * rh) / RS;
    int he = y1 + ((i + 1) * rh + RS - 1) / RS;
    int ws = x1 + (j * rw) / RS;
    int we = x1 + ((j + 1) * rw + RS - 1) / RS;

    const float* fplane = features + (size_t)(b * C + c) * (size_t)(H * W);

    // 3x3 clamped unconditional loads -> 9 independent loads in flight.
    float m = -FLT_MAX;
#pragma unroll
    for (int dr = 0; dr < 3; ++dr) {
        int r = min(hs + dr, he - 1);
        const float* row = fplane + r * W;
#pragma unroll
        for (int dq = 0; dq < 3; ++dq) {
            int q = min(ws + dq, we - 1);
            m = fmaxf(m, row[q]);
        }
    }

    out[idx] = m;
}

extern "C" void kernel_launch(void* const* d_in, const int* in_sizes, int n_in,
                              void* d_out, int out_size, void* d_ws, size_t ws_size,
                              hipStream_t stream) {
    const float* features = (const float*)d_in[0];
    const float* boxes    = (const float*)d_in[1];
    const int*   img_sz   = (const int*)d_in[2];
    float* out = (float*)d_out;

    int total = out_size;               // 128 * 256 * 7 * 7 = 1,605,632
    int block = 256;
    int grid = (total + block - 1) / block;
    roi_pool_kernel<<<grid, block, 0, stream>>>(features, boxes, img_sz, out, total);
}

// Round 4
// 15.403 us; speedup vs baseline: 1.6879x; 1.1556x over previous
//
#include <hip/hip_runtime.h>
#include <cfloat>
#include <cmath>

#define RS 7   // ROI pool output size

// features: (B=2, C=256, H=50, W=50) f32
// boxes:    (B=2, Nb=64, 4) f32  -> N=128 boxes
// out:      (N=128, C=256, 7, 7) f32
//
// One thread per output element, runtime-bounded bin loops (minimal loads:
// avg ~1.7 elems/bin; branch-free 3x3 variant measured SLOWER).
// Box load issued early to overlap its latency with index math.
__global__ __launch_bounds__(256, 8)
void roi_pool_kernel(const float* __restrict__ features,
                     const float* __restrict__ boxes,
                     const int* __restrict__ image_size_p,
                     float* __restrict__ out,
                     int total) {
    int idx = blockIdx.x * blockDim.x + threadIdx.x;
    if (idx >= total) return;

    const int C = 256, H = 50, W = 50;

    // uniform scalar load — issues immediately
    float img = (float)image_size_p[0];

    // decompose just enough to get n, then issue the box load ASAP
    unsigned u = (unsigned)idx;
    unsigned cell = u / 49u;            // (n*C + c)
    unsigned n = cell >> 8;             // box index 0..127
    float4 bb = *reinterpret_cast<const float4*>(boxes + n * 4);

    unsigned rem = u - cell * 49u;      // i*7 + j
    unsigned i = rem / 7u;
    unsigned j = rem - i * 7u;
    unsigned c = cell & (C - 1);
    unsigned b = n >> 6;

    float scale_h = (float)H / img;     // 0.0625 for 800
    float scale_w = (float)W / img;

    // jnp.round = round half to even = rintf (FE_TONEAREST default)
    int x1 = max(0, (int)rintf(bb.x * scale_w));
    int y1 = max(0, (int)rintf(bb.y * scale_h));
    int x2 = min(W, (int)rintf((bb.x + bb.z) * scale_w) + 1);
    int y2 = min(H, (int)rintf((bb.y + bb.w) * scale_h) + 1);
    if (x2 <= x1) x2 = min(x1 + 1, W);
    if (y2 <= y1) y2 = min(y1 + 1, H);

    int rh = y2 - y1;
    int rw = x2 - x1;

    int hs = y1 + ((int)i * rh) / RS;
    int he = y1 + (((int)i + 1) * rh + RS - 1) / RS;
    int ws = x1 + ((int)j * rw) / RS;
    int we = x1 + (((int)j + 1) * rw + RS - 1) / RS;

    const float* fplane = features + (((b << 8) | c) * (unsigned)(H * W));

    float m = -FLT_MAX;
    for (int r = hs; r < he; ++r) {
        const float* row = fplane + r * W;
        for (int q = ws; q < we; ++q) {
            m = fmaxf(m, row[q]);
        }
    }

    out[idx] = m;
}

extern "C" void kernel_launch(void* const* d_in, const int* in_sizes, int n_in,
                              void* d_out, int out_size, void* d_ws, size_t ws_size,
                              hipStream_t stream) {
    const float* features = (const float*)d_in[0];
    const float* boxes    = (const float*)d_in[1];
    const int*   img_sz   = (const int*)d_in[2];
    float* out = (float*)d_out;

    int total = out_size;               // 128 * 256 * 7 * 7 = 1,605,632
    int block = 256;
    int grid = (total + block - 1) / block;
    roi_pool_kernel<<<grid, block, 0, stream>>>(features, boxes, img_sz, out, total);
}